// Round 1
// 1293.596 us; speedup vs baseline: 1.4084x; 1.4084x over previous
//
#include <hip/hip_runtime.h>

typedef __attribute__((ext_vector_type(8))) __bf16 bf16x8;
typedef __attribute__((ext_vector_type(4))) float  f32x4;

#define DEVFN __device__ __forceinline__

constexpr int B = 256, I = 256, H = 512, S = 64;
constexpr int G4H = 4 * H;   // 2048 encoder gate cols
constexpr int G4I = 4 * I;   // 1024 decoder gate cols
constexpr int G3I = 3 * I;   // 768 packed decoder gate cols (i,g,o)

// ---- k_step2 dynamic-LDS map (bytes) ----
constexpr int W_OFF    = 0;        // Whh slice: 128 cols x 1024 B (512 k bf16)
constexpr int HS_OFF   = 131072;   // h tile: 16 rows x 1024 B
constexpr int XT_OFF   = 147456;   // xT tile: 16 rows x 512 B (reused as gate stash)
constexpr int LDS_STEP = 155648;   // 152 KB <= 160 KB

struct Params {
  const float* x;        // [B][I][S]      fp32
  const float* Wih_enc;  // [S][4H][I]     fp32
  const float* Whh_enc;  // [S][4H][H]     fp32
  const float* bih_enc;  // [S][4H]
  const float* bhh_enc;  // [S][4H]
  const float* Wih_dec;  // [S][4I][H]     fp32
  const float* bih_dec;  // [S][4I]
  const float* bhh_dec;  // [S][4I]
  __bf16* xT;             // [S][B][I]  bf16
  float*  h32a; float*  h32b;   // [B][H] ping-pong (fp32 h for cell update)
  __bf16* h16a; __bf16* h16b;   // [B][H] ping-pong (bf16 h for MFMA)
  __bf16* enc;            // [S][B][H]  bf16: elu(h_t), then AR-filtered in place
  float*  hd;             // [S][B][I]  fp32
  __bf16* Whh16;          // [S][4H][H] bf16 (preconverted)
  __bf16* Wdec16;         // [S][3I][H] bf16 (preconverted, gates i,g,o packed)
  float*  out;            // [B][I][S]  fp32
};

DEVFN float sigmoidf_(float x) { return 1.0f / (1.0f + __expf(-x)); }
DEVFN float tanhf_(float x) { float e = __expf(2.0f * x); return 1.0f - 2.0f / (e + 1.0f); }

// load 8 fp32, convert to bf16x8 (RNE via (__bf16) cast)
DEVFN bf16x8 loadw8(const float* p) {
  float4 a = *(const float4*)p;
  float4 b = *(const float4*)(p + 4);
  bf16x8 r;
  r[0] = (__bf16)a.x; r[1] = (__bf16)a.y; r[2] = (__bf16)a.z; r[3] = (__bf16)a.w;
  r[4] = (__bf16)b.x; r[5] = (__bf16)b.y; r[6] = (__bf16)b.z; r[7] = (__bf16)b.w;
  return r;
}

// async global->LDS, 16B per lane. LDS dest must be linear in lane order.
DEVFN void dma16(const void* g, void* l) {
  __builtin_amdgcn_global_load_lds((const __attribute__((address_space(1))) unsigned int*)g,
                                   (__attribute__((address_space(3))) unsigned int*)l, 16, 0, 0);
}

// ---------------- weight preconversion kernels ----------------
// fp32 -> bf16 linear, 8 elems/thread, grid covers exactly.
__global__ __launch_bounds__(512) void k_cvt(const float* __restrict__ src,
                                             __bf16* __restrict__ dst) {
  size_t i = ((size_t)blockIdx.x * 512 + threadIdx.x) * 8;
  *(bf16x8*)(dst + i) = loadw8(src + i);
}

// Wih_dec [S][4I][H] fp32 -> packed [S][3I][H] bf16, gates {i,g,o}
__global__ __launch_bounds__(512) void k_cvt_dec(const float* __restrict__ src,
                                                 __bf16* __restrict__ dst) {
  size_t idx = (size_t)blockIdx.x * 512 + threadIdx.x;   // [0, 3145728)
  int k8  = (int)(idx & 63) * 8;
  int row = (int)(idx >> 6);                             // s*768 + g3*256 + j
  int s = row / 768; int rr = row - s * 768;
  int g3 = rr >> 8; int j = rr & 255;
  int gate = (g3 == 0) ? 0 : (g3 + 1);                   // {0,2,3} in 4I layout
  const float* sp = src + (((size_t)s * G4I) + (size_t)gate * I + j) * H + k8;
  *(bf16x8*)(dst + (size_t)row * H + k8) = loadw8(sp);
}

// ---------------- phase: transpose x[B][I][S] (fp32) -> xT[S][B][I] (bf16) ----
DEVFN void phase_transpose(const Params& P, int job, float* smemf) {
  __bf16* tile = (__bf16*)smemf;            // [64][66] bf16
  const int tid = threadIdx.x;
  const int b = job >> 2, i0 = (job & 3) * 64;
#pragma unroll
  for (int rep = 0; rep < 8; ++rep) {
    int idx = tid + rep * 512;
    int ii = idx >> 6, tt = idx & 63;
    tile[ii * 66 + tt] = (__bf16)P.x[((size_t)(b * I + i0 + ii)) * S + tt];
  }
  __syncthreads();
#pragma unroll
  for (int rep = 0; rep < 8; ++rep) {
    int idx = tid + rep * 512;
    int tt = idx >> 6, ii = idx & 63;
    P.xT[((size_t)tt * B + b) * I + i0 + ii] = tile[ii * 66 + tt];
  }
}

// ---------------- legacy encoder step (fallback path, unchanged) ----------------
DEVFN void phase_step(const Params& P, int t, int job, float* smem) {
  const int tid = threadIdx.x;
  const int g = job >> 7, r = job & 7, bt = (job >> 3) & 15;
  const int jt = g * 8 + r;
  const int b0 = bt * 16, j0 = jt * 32;
  const int wave = tid >> 6, lane = tid & 63;
  const int e = wave >> 1, ct = wave & 1;
  const int ncol = lane & 15, quad = lane >> 4;
  const int gcol = e * H + j0 + ct * 16 + ncol;
  const float*  h32r = (t & 1) ? P.h32b : P.h32a;
  float*        h32w = (t & 1) ? P.h32a : P.h32b;
  const __bf16* h16r = (t & 1) ? P.h16b : P.h16a;
  __bf16*       h16w = (t & 1) ? P.h16a : P.h16b;

  float bias = P.bih_enc[t * G4H + gcol] + P.bhh_enc[t * G4H + gcol];
  f32x4 acc = {bias, bias, bias, bias};
  const int m = ncol;
  const __bf16* aRow1 = P.xT + ((size_t)t * B + b0 + m) * I + quad * 8;
  const float*  bRow1 = P.Wih_enc + ((size_t)t * G4H + gcol) * I + quad * 8;
#pragma unroll
  for (int kk = 0; kk < I; kk += 32) {
    bf16x8 af = *(const bf16x8*)(aRow1 + kk);
    bf16x8 bf = loadw8(bRow1 + kk);
    acc = __builtin_amdgcn_mfma_f32_16x16x32_bf16(af, bf, acc, 0, 0, 0);
  }
  const __bf16* aRow2 = h16r + (size_t)(b0 + m) * H + quad * 8;
  const float*  bRow2 = P.Whh_enc + ((size_t)t * G4H + gcol) * H + quad * 8;
#pragma unroll
  for (int kk = 0; kk < H; kk += 32) {
    bf16x8 af = *(const bf16x8*)(aRow2 + kk);
    bf16x8 bf = loadw8(bRow2 + kk);
    acc = __builtin_amdgcn_mfma_f32_16x16x32_bf16(af, bf, acc, 0, 0, 0);
  }
  float* sm = smem + (e * 2 + ct) * 256;
#pragma unroll
  for (int rr = 0; rr < 4; ++rr) sm[(quad * 4 + rr) * 16 + ncol] = acc[rr];
  __syncthreads();
  {
    const int row = tid >> 5, j = tid & 31;
    const int o = (j >> 4) * 256 + row * 16 + (j & 15);
    float gi = smem[o], gf = smem[512 + o], gg = smem[1024 + o], go = smem[1536 + o];
    size_t hidx = (size_t)(b0 + row) * H + j0 + j;
    float hp = h32r[hidx];
    float c  = sigmoidf_(gf) * hp + sigmoidf_(gi) * tanhf_(gg);
    float hn = sigmoidf_(go) * tanhf_(c);
    h32w[hidx] = hn;
    h16w[hidx] = (__bf16)hn;
    float el = hn > 0.0f ? hn : (__expf(hn) - 1.0f);
    P.enc[((size_t)t * B + b0 + row) * H + j0 + j] = (__bf16)el;
  }
}

// ---------------- fast encoder step: DMA-staged, LDS-resident Whh ----------------
// grid 256 x 512thr (8 waves), 152 KB dynamic LDS, 1 block/CU.
// Stage order per thread: xT(1 issue), h(2), Whh(16). vmcnt(16)+s_barrier releases
// the x-part (Wih streamed fp32) under the in-flight Whh DMA; __syncthreads()
// (full drain) gates the LDS-only h-part. All LDS tiles XOR-swizzled on the
// *source* address (st-swizzle: byte ^= (row&7)<<4) so ds_read_b128 is ~2-way.
__global__ __launch_bounds__(512) void k_step2(Params P, int t) {
  extern __shared__ char sm[];
  const int tid = threadIdx.x;
  const int job = blockIdx.x;
  const int g = job >> 7, r = job & 7, bt = (job >> 3) & 15;
  const int jt = g * 8 + r;
  const int b0 = bt * 16, j0 = jt * 32;
  const int wave = tid >> 6, lane = tid & 63;
  const int e = wave >> 1, ct = wave & 1;
  const int ncol = lane & 15, quad = lane >> 4;
  const int gcol = e * H + j0 + ct * 16 + ncol;
  const float*  h32r = (t & 1) ? P.h32b : P.h32a;
  float*        h32w = (t & 1) ? P.h32a : P.h32b;
  const __bf16* h16r = (t & 1) ? P.h16b : P.h16a;
  __bf16*       h16w = (t & 1) ? P.h16a : P.h16b;

  // epilogue coords; early h_prev load overlaps the staging
  const int erow = tid >> 5, ej = tid & 31;
  const size_t ehidx = (size_t)(b0 + erow) * H + j0 + ej;
  const float hp = h32r[ehidx];

  // ---- stage xT tile: 16 rows x 512 B
  {
    const int d = tid * 16;
    const int rr = d >> 9, c = (d & 511) ^ ((rr & 7) << 4);
    dma16((const char*)(P.xT + ((size_t)t * B + b0 + rr) * I) + c, sm + XT_OFF + d);
  }
  // ---- stage h tile: 16 rows x 1024 B
#pragma unroll
  for (int i = 0; i < 2; ++i) {
    const int d = (i * 512 + tid) * 16;
    const int rr = d >> 10, c = (d & 1023) ^ ((rr & 7) << 4);
    dma16((const char*)(h16r + (size_t)(b0 + rr) * H) + c, sm + HS_OFF + d);
  }
  __builtin_amdgcn_sched_barrier(0);
  // ---- stage Whh slice: 128 cols x 1024 B (colIdx = e*32 + jj)
#pragma unroll
  for (int i = 0; i < 16; ++i) {
    const int d = (i * 512 + tid) * 16;
    const int ci = d >> 10, c = (d & 1023) ^ ((ci & 7) << 4);
    const int gc = (ci >> 5) * H + j0 + (ci & 31);
    dma16((const char*)(P.Whh16 + ((size_t)t * G4H + gc) * H) + c, sm + W_OFF + d);
  }
  __builtin_amdgcn_sched_barrier(0);
  asm volatile("s_waitcnt vmcnt(16)" ::: "memory");   // xT + h landed; Whh in flight
  __builtin_amdgcn_sched_barrier(0);
  __builtin_amdgcn_s_barrier();
  __builtin_amdgcn_sched_barrier(0);

  float bias = P.bih_enc[t * G4H + gcol] + P.bhh_enc[t * G4H + gcol];
  f32x4 acc = {bias, bias, bias, bias};
  const int m = ncol;
  const int swa = (m & 7) << 4;
  // x-part: A from LDS, B streamed fp32 (covers the Whh DMA latency)
  const float* bRow1 = P.Wih_enc + ((size_t)t * G4H + gcol) * I + quad * 8;
#pragma unroll
  for (int kk = 0; kk < I; kk += 32) {
    bf16x8 af = *(const bf16x8*)(sm + XT_OFF + m * 512 + ((kk * 2 + quad * 16) ^ swa));
    bf16x8 bf = loadw8(bRow1 + kk);
    acc = __builtin_amdgcn_mfma_f32_16x16x32_bf16(af, bf, acc, 0, 0, 0);
  }
  __syncthreads();                      // drains vmcnt(0): Whh slice resident
  const int ci = e * 32 + ct * 16 + ncol;
  const int swb = (ci & 7) << 4;
  // h-part: entirely LDS-resident
#pragma unroll
  for (int kk = 0; kk < H; kk += 32) {
    const int wo = kk * 2 + quad * 16;
    bf16x8 af = *(const bf16x8*)(sm + HS_OFF + m * 1024 + (wo ^ swa));
    bf16x8 bf = *(const bf16x8*)(sm + W_OFF + ci * 1024 + (wo ^ swb));
    acc = __builtin_amdgcn_mfma_f32_16x16x32_bf16(af, bf, acc, 0, 0, 0);
  }
  // gate stash (reuse xT region; xT reads all completed before mid-sync)
  float* gsm = (float*)(sm + XT_OFF);
  float* smw = gsm + (e * 2 + ct) * 256;
#pragma unroll
  for (int rr = 0; rr < 4; ++rr) smw[(quad * 4 + rr) * 16 + ncol] = acc[rr];
  __syncthreads();
  {
    const int o = (ej >> 4) * 256 + erow * 16 + (ej & 15);
    float gi = gsm[o], gf = gsm[512 + o], gg = gsm[1024 + o], go = gsm[1536 + o];
    float c  = sigmoidf_(gf) * hp + sigmoidf_(gi) * tanhf_(gg);
    float hn = sigmoidf_(go) * tanhf_(c);
    h32w[ehidx] = hn;
    h16w[ehidx] = (__bf16)hn;
    float el = hn > 0.0f ? hn : (__expf(hn) - 1.0f);
    P.enc[((size_t)t * B + b0 + erow) * H + j0 + ej] = (__bf16)el;
  }
}

// ---------------- phase: AR filter over enc (in place, bf16, fp32 math) ------
DEVFN void phase_ar(const Params& P) {
  int gid = blockIdx.x * blockDim.x + threadIdx.x;
  int b = gid >> 9, hi = gid & 511;
  float prev = (float)P.enc[((size_t)60 * B + b) * H + hi];
#pragma unroll
  for (int a = 0; a < 16; ++a) {
    size_t idx = ((size_t)(4 * a) * B + b) * H + hi;
    float cur = (float)P.enc[idx];
    float nv = 0.5f * (cur + prev);
    P.enc[idx] = (__bf16)nv;
    prev = nv;
  }
}

// ---------------- decoder gates -> hd; FAST uses packed bf16 weights ---------
template <bool FAST>
__global__ __launch_bounds__(512) void k_dec_t(Params P) {
  __shared__ float smem[6144];
  const int tid = threadIdx.x;
  const int job = blockIdx.x;
  const int g = job >> 5, bt = (job >> 3) & 3, r = job & 7;
  const int sjt = g * 8 + r;
  const int s = sjt >> 3, jt = sjt & 7;
  const int b0 = bt * 64, j0 = jt * 32;
  const int wave = tid >> 6, lane = tid & 63;
  const int rt = wave >> 1, chalf = wave & 1;
  const int ncol = lane & 15, quad = lane >> 4;
  const int arow = b0 + rt * 16 + ncol;
  const __bf16* aRow = P.enc + ((size_t)(63 - s) * B + arow) * H + quad * 8;

  f32x4 acc[3];
  int gcols[3], pcols[3];
#pragma unroll
  for (int cc = 0; cc < 3; ++cc) {
    const int c = chalf * 3 + cc;
    const int e3 = c >> 1;
    const int gate = (e3 == 0) ? 0 : (e3 + 1);
    const int jw = j0 + (c & 1) * 16 + ncol;
    gcols[cc] = gate * I + jw;
    pcols[cc] = e3 * I + jw;
    float bias = P.bih_dec[s * G4I + gcols[cc]] + P.bhh_dec[s * G4I + gcols[cc]];
    acc[cc] = {bias, bias, bias, bias};
  }
  const float*  bBase = P.Wih_dec + (size_t)s * G4I * H + quad * 8;
  const __bf16* pBase = P.Wdec16  + (size_t)s * G3I * H + quad * 8;
#pragma unroll
  for (int kk = 0; kk < H; kk += 32) {
    bf16x8 af = *(const bf16x8*)(aRow + kk);
#pragma unroll
    for (int cc = 0; cc < 3; ++cc) {
      bf16x8 bf;
      if constexpr (FAST) bf = *(const bf16x8*)(pBase + (size_t)pcols[cc] * H + kk);
      else                bf = loadw8(bBase + (size_t)gcols[cc] * H + kk);
      acc[cc] = __builtin_amdgcn_mfma_f32_16x16x32_bf16(af, bf, acc[cc], 0, 0, 0);
    }
  }
#pragma unroll
  for (int cc = 0; cc < 3; ++cc) {
    const int c = chalf * 3 + cc;
    const int e3 = c >> 1;
    const int jw = (c & 1) * 16 + ncol;
    float* smv = smem + e3 * 2048 + (rt * 16) * 32 + jw;
#pragma unroll
    for (int rr = 0; rr < 4; ++rr) smv[(quad * 4 + rr) * 32] = acc[cc][rr];
  }
  __syncthreads();
  {
    const int row = tid >> 3, jb = (tid & 7) * 4;
    float tmp[4];
#pragma unroll
    for (int u = 0; u < 4; ++u) {
      int j = jb + u;
      float gi = smem[row * 32 + j];
      float gg = smem[2048 + row * 32 + j];
      float go = smem[4096 + row * 32 + j];
      float cv = sigmoidf_(gi) * tanhf_(gg);
      tmp[u] = sigmoidf_(go) * tanhf_(cv);
    }
    float* hout = &P.hd[((size_t)s * B + b0 + row) * I + j0 + jb];
    *(float4*)hout = make_float4(tmp[0], tmp[1], tmp[2], tmp[3]);
  }
}

// ---------------- phase: blockwise cumsum + tanh + transpose out (fp32) ------
DEVFN void phase_out(const Params& P, int job, float* smem) {
  const int tid = threadIdx.x;
  const int b = job >> 2, i0 = (job & 3) * 64;
#pragma unroll
  for (int rep = 0; rep < 8; ++rep) {
    int idx = tid + rep * 512;
    int tt = idx >> 6, ii = idx & 63;
    smem[tt * 66 + ii] = P.hd[((size_t)tt * B + b) * I + i0 + ii];
  }
  __syncthreads();
#pragma unroll
  for (int rep = 0; rep < 2; ++rep) {
    int a = tid & 15;
    int ii = (tid >> 4) + rep * 32;
    float r0 = smem[(4 * a + 0) * 66 + ii];
    float r1 = r0 + smem[(4 * a + 1) * 66 + ii];
    float r2 = r1 + smem[(4 * a + 2) * 66 + ii];
    float r3 = r2 + smem[(4 * a + 3) * 66 + ii];
    float4 v = make_float4(tanhf_(r3), tanhf_(r2), tanhf_(r1), tanhf_(r0));
    *(float4*)&P.out[((size_t)(b * I + i0 + ii)) * S + (60 - 4 * a)] = v;
  }
}

// ---------------- kernels ----------------
__global__ __launch_bounds__(512) void k_transpose(Params P) {
  __shared__ float sm[2112];
  phase_transpose(P, blockIdx.x, sm);
}
__global__ __launch_bounds__(512) void k_step_legacy(Params P, int t) {
  __shared__ float sm[2048];
  phase_step(P, t, blockIdx.x, sm);
}
__global__ __launch_bounds__(512) void k_ar(Params P) { phase_ar(P); }
__global__ __launch_bounds__(512) void k_out(Params P) {
  __shared__ float sm[4224];
  phase_out(P, blockIdx.x, sm);
}

extern "C" void kernel_launch(void* const* d_in, const int* in_sizes, int n_in,
                              void* d_out, int out_size, void* d_ws, size_t ws_size,
                              hipStream_t stream) {
  (void)in_sizes; (void)n_in; (void)out_size;
  char* ws = (char*)d_ws;
  Params P;
  P.x       = (const float*)d_in[0];
  P.Wih_enc = (const float*)d_in[1];
  P.Whh_enc = (const float*)d_in[2];
  P.bih_enc = (const float*)d_in[3];
  P.bhh_enc = (const float*)d_in[4];
  P.Wih_dec = (const float*)d_in[5];
  // d_in[6] = Whh_dec: unused by the reference
  P.bih_dec = (const float*)d_in[7];
  P.bhh_dec = (const float*)d_in[8];

  size_t off = 0;
  P.xT     = (__bf16*)(ws + off); off += (size_t)S * B * I * 2;      //  8,388,608
  P.h32a   = (float*) (ws + off); off += (size_t)B * H * 4;          //    524,288
  P.h16a   = (__bf16*)(ws + off); off += (size_t)B * H * 2;          //    262,144
  P.h32b   = (float*) (ws + off); off += (size_t)B * H * 4;
  P.h16b   = (__bf16*)(ws + off); off += (size_t)B * H * 2;
  P.enc    = (__bf16*)(ws + off); off += (size_t)S * B * H * 2;      // 16,777,216
  P.hd     = (float*) (ws + off); off += (size_t)S * B * I * 4;      // 16,777,216
  P.Whh16  = (__bf16*)(ws + off); off += (size_t)S * G4H * H * 2;    // 134,217,728
  P.Wdec16 = (__bf16*)(ws + off); off += (size_t)S * G3I * H * 2;    //  50,331,648
  P.out    = (float*)d_out;
  const size_t NEED_FAST = off;   // 228,065,280 B

  bool fast = ws_size >= NEED_FAST;
  if (fast &&
      hipFuncSetAttribute(reinterpret_cast<const void*>(&k_step2),
                          hipFuncAttributeMaxDynamicSharedMemorySize,
                          (int)LDS_STEP) != hipSuccess) {
    fast = false;
  }

  // zero h slot 0 (h32a + h16a are contiguous: 512KB + 256KB)
  hipMemsetAsync((char*)P.h32a, 0, (size_t)B * H * 4 + (size_t)B * H * 2, stream);

  if (fast) {
    k_cvt<<<16384, 512, 0, stream>>>(P.Whh_enc, P.Whh16);            // 67.1M elems
    k_transpose<<<1024, 512, 0, stream>>>(P);
    for (int t = 0; t < S; ++t) k_step2<<<256, 512, LDS_STEP, stream>>>(P, t);
    k_ar<<<256, 512, 0, stream>>>(P);
    k_cvt_dec<<<6144, 512, 0, stream>>>(P.Wih_dec, P.Wdec16);        // L3-warm for k_dec
    k_dec_t<true><<<2048, 512, 0, stream>>>(P);
    k_out<<<1024, 512, 0, stream>>>(P);
  } else {
    k_transpose<<<1024, 512, 0, stream>>>(P);
    for (int t = 0; t < S; ++t) k_step_legacy<<<256, 512, 0, stream>>>(P, t);
    k_ar<<<256, 512, 0, stream>>>(P);
    k_dec_t<false><<<2048, 512, 0, stream>>>(P);
    k_out<<<1024, 512, 0, stream>>>(P);
  }
}